// Round 1
// baseline (1046.328 us; speedup 1.0000x reference)
//
#include <hip/hip_runtime.h>

#define BATCH  16
#define SEQ    4096
#define DIM    64
#define NHASH  8
#define NCHUNK 512   // chunks per batch row (NHASH * SEQ / 64)

// ---------------------------------------------------------------------------
// Kernel 1: LSH hashing. One thread per (b,t) token. rotations are read with
// wave-uniform indices -> scalar loads through sL1. Per-thread q row lives in
// a private LDS column (dynamic f-indexing without VGPR-array spills).
// buckets[(b*8+h)*4096 + t] = argmax over [r, -r] (first-max wins, like jnp).
// ---------------------------------------------------------------------------
__global__ __launch_bounds__(256) void lsh_hash_kernel(
    const float* __restrict__ qk, const float* __restrict__ rot,
    int* __restrict__ buckets)
{
    __shared__ float qs[256 * DIM];
    int tid = threadIdx.x;
    int gid = blockIdx.x * 256 + tid;      // b*4096 + t
    int b = gid >> 12, t = gid & 4095;

    const float4* src = (const float4*)(qk + (size_t)gid * DIM);
#pragma unroll
    for (int u = 0; u < 16; ++u) {
        float4 x = src[u];
        qs[(4*u + 0) * 256 + tid] = x.x;
        qs[(4*u + 1) * 256 + tid] = x.y;
        qs[(4*u + 2) * 256 + tid] = x.z;
        qs[(4*u + 3) * 256 + tid] = x.w;
    }
    // no __syncthreads needed: each thread reads only its own column

    for (int h = 0; h < NHASH; ++h) {
        float acc[32];
#pragma unroll
        for (int i = 0; i < 32; ++i) acc[i] = 0.f;
        for (int f = 0; f < DIM; ++f) {
            float qf = qs[f * 256 + tid];
            const float* rp = rot + (f * NHASH + h) * 32;   // wave-uniform addr
#pragma unroll
            for (int i = 0; i < 32; ++i) acc[i] = fmaf(qf, rp[i], acc[i]);
        }
        float best = acc[0]; int bi = 0;
#pragma unroll
        for (int i = 1; i < 32; ++i) { if (acc[i] > best) { best = acc[i]; bi = i; } }
#pragma unroll
        for (int i = 0; i < 32; ++i) { float nv = -acc[i]; if (nv > best) { best = nv; bi = i + 32; } }
        buckets[((size_t)b * NHASH + h) * SEQ + t] = bi;
    }
}

// ---------------------------------------------------------------------------
// Kernel 2: stable counting sort per (b,h). One wave per block. Lane l owns
// tokens [64l, 64l+64) (contiguous -> stability). hist[lane][bucket] local
// histograms, column prefix over lanes by lane==bucket, then ordered scatter.
// st[(b*8+h)*4096 + pos] = original token t, sorted by (bucket, t).
// ---------------------------------------------------------------------------
__global__ __launch_bounds__(64) void lsh_sort_kernel(
    const int* __restrict__ buckets, int* __restrict__ st)
{
    int bh = blockIdx.x;                 // b*8 + h
    int lane = threadIdx.x;              // 0..63
    const int* bp = buckets + (size_t)bh * SEQ;
    __shared__ int hist[64 * 64];        // [lane][bucket]
    __shared__ int tot[64];
    __shared__ int base[64];

    for (int i = 0; i < 64; ++i) hist[(lane << 6) + i] = 0;
    __syncthreads();
    for (int u = 0; u < 64; ++u) {
        int tt = (lane << 6) + u;
        hist[(lane << 6) + bp[tt]] += 1;     // private region, no race
    }
    __syncthreads();
    {   // lane == bucket: exclusive prefix over lanes, total per bucket
        int run = 0;
        for (int l = 0; l < 64; ++l) {
            int idx = (l << 6) + lane;
            int c0 = hist[idx];
            hist[idx] = run;
            run += c0;
        }
        tot[lane] = run;
    }
    __syncthreads();
    if (lane == 0) {
        int r = 0;
        for (int i = 0; i < 64; ++i) { base[i] = r; r += tot[i]; }
    }
    __syncthreads();
    int* op = st + (size_t)bh * SEQ;
    for (int u = 0; u < 64; ++u) {
        int tt = (lane << 6) + u;
        int bb = bp[tt];
        int idx = (lane << 6) + bb;
        int pos = base[bb] + hist[idx];
        hist[idx] = pos - base[bb] + 1;
        op[pos] = tt;
    }
}

// ---------------------------------------------------------------------------
// Kernel 3: chunked attention. Block = one (b, chunk). Keys processed in two
// 64-row halves: own chunk, then look-back chunk (c-1 mod 512). Accumulates
// numerator N[b][t][d] += sum_j exp(dots)*v and denominator D[b][t] += sum_j
// exp(dots) with global fp32 atomics (the logsumexp combine collapses to N/D).
// ---------------------------------------------------------------------------
__global__ __launch_bounds__(256, 2) void lsh_attn_kernel(
    const float* __restrict__ qk, const float* __restrict__ v,
    const int* __restrict__ st, float* __restrict__ Nbuf, float* __restrict__ Dbuf)
{
    __shared__ float Qs[64 * 64];
    __shared__ float Ks[64 * 64];
    __shared__ float Vs[64 * 64];
    __shared__ float Ps[64 * 64];
    __shared__ int   tq[64];
    __shared__ int   tk[64];
    __shared__ float Drow[64];

    int tid = threadIdx.x;
    int bc = blockIdx.x;
    int b = bc >> 9, c = bc & (NCHUNK - 1);
    int cm = (c + NCHUNK - 1) & (NCHUNK - 1);

    const int*   stb = st + (size_t)b * (NHASH * SEQ);
    const float* qkb = qk + (size_t)b * SEQ * DIM;
    const float* vb  = v  + (size_t)b * SEQ * DIM;

    if (tid < 64) { tq[tid] = stb[c * 64 + tid]; Drow[tid] = 0.f; }
    __syncthreads();

    {   // load Q (unnormalized): 4 threads/row, 16 floats each
        int r = tid >> 2, s = tid & 3;
        const float4* s4 = (const float4*)(qkb + (size_t)tq[r] * DIM + s * 16);
        float4* d4 = (float4*)(Qs + r * 64 + s * 16);
        d4[0] = s4[0]; d4[1] = s4[1]; d4[2] = s4[2]; d4[3] = s4[3];
    }

    int ty = tid >> 4, tx = tid & 15;
    float acc[4][4];
#pragma unroll
    for (int a = 0; a < 4; ++a)
        acc[a][0] = acc[a][1] = acc[a][2] = acc[a][3] = 0.f;

    for (int half = 0; half < 2; ++half) {
        int ck = half ? cm : c;
        __syncthreads();                       // Q ready / prev-half consumers done
        if (tid < 64) tk[tid] = stb[ck * 64 + tid];
        __syncthreads();                       // tk visible
        {   // load K (L2-normalized) and V: 4 threads/row, 16 floats each
            int r = tid >> 2, s = tid & 3;
            int trow = tk[r];
            const float4* k4 = (const float4*)(qkb + (size_t)trow * DIM + s * 16);
            float4 a0 = k4[0], a1 = k4[1], a2 = k4[2], a3 = k4[3];
            float ss = a0.x*a0.x + a0.y*a0.y + a0.z*a0.z + a0.w*a0.w
                     + a1.x*a1.x + a1.y*a1.y + a1.z*a1.z + a1.w*a1.w
                     + a2.x*a2.x + a2.y*a2.y + a2.z*a2.z + a2.w*a2.w
                     + a3.x*a3.x + a3.y*a3.y + a3.z*a3.z + a3.w*a3.w;
            ss += __shfl_xor(ss, 1);
            ss += __shfl_xor(ss, 2);
            float sc = 1.0f / fmaxf(sqrtf(ss), 1e-12f);
            float4* kd = (float4*)(Ks + r * 64 + s * 16);
            a0.x *= sc; a0.y *= sc; a0.z *= sc; a0.w *= sc;
            a1.x *= sc; a1.y *= sc; a1.z *= sc; a1.w *= sc;
            a2.x *= sc; a2.y *= sc; a2.z *= sc; a2.w *= sc;
            a3.x *= sc; a3.y *= sc; a3.z *= sc; a3.w *= sc;
            kd[0] = a0; kd[1] = a1; kd[2] = a2; kd[3] = a3;
            const float4* v4 = (const float4*)(vb + (size_t)trow * DIM + s * 16);
            float4* vd = (float4*)(Vs + r * 64 + s * 16);
            vd[0] = v4[0]; vd[1] = v4[1]; vd[2] = v4[2]; vd[3] = v4[3];
        }
        __syncthreads();                       // K/V staged
        {   // dots: thread tile i = ty+16a (4 rows) x j = 4tx+jj (4 cols)
            float dt[4][4];
#pragma unroll
            for (int a = 0; a < 4; ++a)
                dt[a][0] = dt[a][1] = dt[a][2] = dt[a][3] = 0.f;
            for (int k = 0; k < 64; k += 4) {
                float4 qv[4], kv[4];
#pragma unroll
                for (int a = 0; a < 4; ++a)
                    qv[a] = *(const float4*)(Qs + (ty + 16*a) * 64 + k);
#pragma unroll
                for (int jj = 0; jj < 4; ++jj)
                    kv[jj] = *(const float4*)(Ks + (4*tx + jj) * 64 + k);
#pragma unroll
                for (int a = 0; a < 4; ++a) {
                    const float* qa = (const float*)&qv[a];
#pragma unroll
                    for (int jj = 0; jj < 4; ++jj) {
                        const float* kj = (const float*)&kv[jj];
                        dt[a][jj] = fmaf(qa[0], kj[0],
                                    fmaf(qa[1], kj[1],
                                    fmaf(qa[2], kj[2],
                                    fmaf(qa[3], kj[3], dt[a][jj]))));
                    }
                }
            }
            // mask self-attention, exp, write P, row-sum into Drow
#pragma unroll
            for (int a = 0; a < 4; ++a) {
                int i = ty + 16*a;
                int ti = tq[i];
                float4 pv;
                float* pp = (float*)&pv;
                float rs = 0.f;
#pragma unroll
                for (int jj = 0; jj < 4; ++jj) {
                    int j = 4*tx + jj;
                    float p = (ti == tk[j]) ? 0.f : __expf(dt[a][jj] * 0.125f);
                    pp[jj] = p;
                    rs += p;
                }
                *(float4*)(Ps + i * 64 + 4*tx) = pv;
                atomicAdd(&Drow[i], rs);
            }
        }
        __syncthreads();                       // P staged
        {   // PV accumulate: thread tile i = ty+16a x d = 4tx..4tx+3
            for (int j = 0; j < 64; j += 4) {
                float4 pr[4], vr[4];
#pragma unroll
                for (int a = 0; a < 4; ++a)
                    pr[a] = *(const float4*)(Ps + (ty + 16*a) * 64 + j);
#pragma unroll
                for (int jj = 0; jj < 4; ++jj)
                    vr[jj] = *(const float4*)(Vs + (j + jj) * 64 + 4*tx);
#pragma unroll
                for (int a = 0; a < 4; ++a) {
                    const float* pa = (const float*)&pr[a];
#pragma unroll
                    for (int jj = 0; jj < 4; ++jj) {
                        const float* vj = (const float*)&vr[jj];
                        float p = pa[jj];
                        acc[a][0] = fmaf(p, vj[0], acc[a][0]);
                        acc[a][1] = fmaf(p, vj[1], acc[a][1]);
                        acc[a][2] = fmaf(p, vj[2], acc[a][2]);
                        acc[a][3] = fmaf(p, vj[3], acc[a][3]);
                    }
                }
            }
        }
    }
    __syncthreads();
    {   // scatter-accumulate into global N / D
#pragma unroll
        for (int a = 0; a < 4; ++a) {
            int i = ty + 16*a;
            int t = tq[i];
            float* np = Nbuf + ((size_t)b * SEQ + t) * DIM + 4*tx;
            atomicAdd(np + 0, acc[a][0]);
            atomicAdd(np + 1, acc[a][1]);
            atomicAdd(np + 2, acc[a][2]);
            atomicAdd(np + 3, acc[a][3]);
        }
        if (tid < 64) atomicAdd(&Dbuf[(size_t)b * SEQ + tq[tid]], Drow[tid]);
    }
}

// ---------------------------------------------------------------------------
// Kernel 4: out = N / D  (one float4 per thread)
// ---------------------------------------------------------------------------
__global__ __launch_bounds__(256) void lsh_combine_kernel(
    const float* __restrict__ Nbuf, const float* __restrict__ Dbuf,
    float* __restrict__ out)
{
    int gid = blockIdx.x * 256 + threadIdx.x;   // float4 index
    float4 n = ((const float4*)Nbuf)[gid];
    float d = Dbuf[gid >> 4];                   // 16 float4 per token
    float inv = 1.0f / d;
    float4 o;
    o.x = n.x * inv; o.y = n.y * inv; o.z = n.z * inv; o.w = n.w * inv;
    ((float4*)out)[gid] = o;
}

extern "C" void kernel_launch(void* const* d_in, const int* in_sizes, int n_in,
                              void* d_out, int out_size, void* d_ws, size_t ws_size,
                              hipStream_t stream)
{
    const float* qk  = (const float*)d_in[0];
    const float* v   = (const float*)d_in[1];
    const float* rot = (const float*)d_in[2];
    float* out = (float*)d_out;

    char* w = (char*)d_ws;
    // workspace layout (21.3 MB total):
    //   [0, 2MB)      buckets  : int[16*8*4096]
    //   [2MB, 4MB)    st       : int[16*8*4096]
    //   [4MB, 20MB)   Nbuf     : float[16*4096*64]
    //   [20MB, +256K) Dbuf     : float[16*4096]
    int*   buckets = (int*)(w);
    int*   st      = (int*)(w + 2097152);
    float* Nbuf    = (float*)(w + 4194304);
    float* Dbuf    = (float*)(w + 4194304 + 16777216);

    hipMemsetAsync(w + 4194304, 0, 16777216 + 262144, stream);
    lsh_hash_kernel<<<256, 256, 0, stream>>>(qk, rot, buckets);
    lsh_sort_kernel<<<128, 64, 0, stream>>>(buckets, st);
    lsh_attn_kernel<<<8192, 256, 0, stream>>>(qk, v, st, Nbuf, Dbuf);
    lsh_combine_kernel<<<4096, 256, 0, stream>>>(Nbuf, Dbuf, out);
}